// Round 2
// baseline (325.294 us; speedup 1.0000x reference)
//
#include <hip/hip_runtime.h>
#include <cstddef>

constexpr int Bn = 16, Dn = 512, Nn = 4096, Kn = 64;
constexpr float FEPS = 1e-12f;

// ---------------------------------------------------------------------------
// kW: transpose conv_w[K][D] -> wT[D][K] so kA can s_load 16 consecutive k.
// ---------------------------------------------------------------------------
__global__ __launch_bounds__(256) void kW(const float* __restrict__ w,
                                          float* __restrict__ wT) {
  const int idx = blockIdx.x * 256 + threadIdx.x;  // 32768 total
  const int d = idx >> 6, k = idx & 63;
  wT[idx] = w[k * Dn + d];
}

// ---------------------------------------------------------------------------
// kA v2: logits GEMM with W in SGPRs, x read coalesced from global (no LDS
// in the main loop). Fused x-norm + softmax + per-tile mass partials.
//   grid 1024: b = bid>>6, ntile = bid&63 (64 n). 256 thr = 4 waves.
//   wave w handles 16 k; lane = n. acc[16] per lane.
// Writes: assign[b][k][n] (softmax, unscaled), invn[b][n], massp[b][nt][k].
// ---------------------------------------------------------------------------
__global__ __launch_bounds__(256) void kA(const float* __restrict__ x,
                                          const float* __restrict__ wT,
                                          const float* __restrict__ conv_b,
                                          float* __restrict__ assign,
                                          float* __restrict__ invn,
                                          float* __restrict__ massp) {
  __shared__ float red[4][64];
  const int tid = threadIdx.x;
  const int lane = tid & 63;
  const int w = tid >> 6;
  const int kg0 = __builtin_amdgcn_readfirstlane(w << 4);
  const int b = blockIdx.x >> 6;
  const int nt = blockIdx.x & 63;
  const int n0 = nt << 6;
  const float* xp = x + (size_t)b * Dn * Nn + n0 + lane;

  float acc[16];
#pragma unroll
  for (int j = 0; j < 16; ++j) acc[j] = 0.f;
  float ss = 0.f;

#pragma unroll 2
  for (int d = 0; d < Dn; d += 4) {
    float xv[4];
#pragma unroll
    for (int i = 0; i < 4; ++i) xv[i] = xp[(size_t)(d + i) * Nn];
    float wv[4][16];
#pragma unroll
    for (int i = 0; i < 4; ++i)
#pragma unroll
      for (int j = 0; j < 16; ++j) wv[i][j] = wT[(d + i) * Kn + kg0 + j];
#pragma unroll
    for (int i = 0; i < 4; ++i) {
      ss = fmaf(xv[i], xv[i], ss);
#pragma unroll
      for (int j = 0; j < 16; ++j) acc[j] = fmaf(wv[i][j], xv[i], acc[j]);
    }
  }

  // ---- epilogue ----
  const float iv = 1.f / fmaxf(sqrtf(ss), FEPS);
  float cbv[16];
#pragma unroll
  for (int j = 0; j < 16; ++j) cbv[j] = conv_b[kg0 + j];
  float lg[16];
#pragma unroll
  for (int j = 0; j < 16; ++j) lg[j] = fmaf(acc[j], iv, cbv[j]);
  float pmax = lg[0];
#pragma unroll
  for (int j = 1; j < 16; ++j) pmax = fmaxf(pmax, lg[j]);
  red[w][lane] = pmax;
  __syncthreads();
  const float gmax = fmaxf(fmaxf(red[0][lane], red[1][lane]),
                           fmaxf(red[2][lane], red[3][lane]));
  __syncthreads();
  float ex[16];
  float psum = 0.f;
#pragma unroll
  for (int j = 0; j < 16; ++j) {
    ex[j] = expf(lg[j] - gmax);
    psum += ex[j];
  }
  red[w][lane] = psum;
  __syncthreads();
  const float gsum = (red[0][lane] + red[1][lane]) + (red[2][lane] + red[3][lane]);
  const float isum = 1.f / gsum;

  float* ab = assign + (size_t)b * Kn * Nn + n0 + lane;
#pragma unroll
  for (int j = 0; j < 16; ++j) {
    const float a = ex[j] * isum;
    ab[(size_t)(kg0 + j) * Nn] = a;
    // per-(k, ntile) mass partial: 64-lane sum
    float m = a;
#pragma unroll
    for (int off = 1; off < 64; off <<= 1) m += __shfl_xor(m, off);
    if (lane == 0) massp[((b << 6) + nt) * Kn + kg0 + j] = m;
  }
  if (w == 0) invn[(size_t)b * Nn + n0 + lane] = iv;
}

// ---------------------------------------------------------------------------
// kB v2: agg GEMM with assign rows in SGPRs, x read as full 64B lines/lane.
//   grid 1024: b = bid>>6, dt = (bid>>3)&7 (64 d), seg = bid&7 (512 n).
//   4 waves split the seg into 128-n subranges; lane = d. acc[64k]/lane.
// Cross-wave reduce via LDS at the end; writes aggp[seg][b][k][d].
// ---------------------------------------------------------------------------
__global__ __launch_bounds__(256) void kB(const float* __restrict__ x,
                                          const float* __restrict__ assign,
                                          const float* __restrict__ invn,
                                          float* __restrict__ aggp) {
  __shared__ float rb[4][16][64];
  const int tid = threadIdx.x;
  const int lane = tid & 63;
  const int w = tid >> 6;
  const int b = blockIdx.x >> 6;
  const int dt = (blockIdx.x >> 3) & 7;
  const int seg = blockIdx.x & 7;
  const int d = dt * 64 + lane;
  const int nb0 = __builtin_amdgcn_readfirstlane(seg * 512 + w * 128);
  const float* xp = x + (size_t)b * Dn * Nn + (size_t)d * Nn;
  const float* ap = assign + (size_t)b * Kn * Nn;
  const float* ip = invn + (size_t)b * Nn;

  float acc[64];
#pragma unroll
  for (int k = 0; k < 64; ++k) acc[k] = 0.f;

  for (int nc = 0; nc < 128; nc += 16) {
    const int nb = nb0 + nc;
    float4 xq[4];
#pragma unroll
    for (int i = 0; i < 4; ++i)
      xq[i] = *(const float4*)(xp + nb + i * 4);
    float inv16[16];
#pragma unroll
    for (int t = 0; t < 16; ++t) inv16[t] = ip[nb + t];  // uniform -> s_load
    float xv[16];
#pragma unroll
    for (int i = 0; i < 4; ++i) {
      xv[4 * i + 0] = xq[i].x * inv16[4 * i + 0];
      xv[4 * i + 1] = xq[i].y * inv16[4 * i + 1];
      xv[4 * i + 2] = xq[i].z * inv16[4 * i + 2];
      xv[4 * i + 3] = xq[i].w * inv16[4 * i + 3];
    }
#pragma unroll
    for (int k = 0; k < 64; ++k) {
      float av[16];
#pragma unroll
      for (int t = 0; t < 16; ++t) av[t] = ap[(size_t)k * Nn + nb + t];
#pragma unroll
      for (int t = 0; t < 16; ++t) acc[k] = fmaf(av[t], xv[t], acc[k]);
    }
  }

  // ---- cross-wave reduce (4 waves), 16 k at a time ----
  float* outb = aggp + ((size_t)(seg * Bn + b)) * Kn * Dn + dt * 64;
#pragma unroll
  for (int ks = 0; ks < 4; ++ks) {
    __syncthreads();
#pragma unroll
    for (int j = 0; j < 16; ++j) rb[w][j][lane] = acc[ks * 16 + j];
    __syncthreads();
#pragma unroll
    for (int r = 0; r < 4; ++r) {
      const int j = (tid >> 6) * 4 + r;
      const float s = (rb[0][j][lane] + rb[1][j][lane]) +
                      (rb[2][j][lane] + rb[3][j][lane]);
      outb[(size_t)(ks * 16 + j) * Dn + lane] = s;
    }
  }
}

// ---------------------------------------------------------------------------
// kC1: per (b,k): mass from massp; vlad = sum(aggp) - mass*c; intra-norm.
// ---------------------------------------------------------------------------
__device__ __forceinline__ float blockReduceSum(float v, float* sb) {
#pragma unroll
  for (int off = 32; off > 0; off >>= 1) v += __shfl_down(v, off, 64);
  const int lane = threadIdx.x & 63, w = threadIdx.x >> 6;
  if (lane == 0) sb[w] = v;
  __syncthreads();
  if (threadIdx.x == 0) sb[4] = sb[0] + sb[1] + sb[2] + sb[3];
  __syncthreads();
  return sb[4];
}

__global__ __launch_bounds__(256) void kC1(const float* __restrict__ massp,
                                           const float* __restrict__ aggp,
                                           const float* __restrict__ centroids,
                                           float* __restrict__ out,
                                           float* __restrict__ rowsq) {
  __shared__ float sb[5];
  const int tid = threadIdx.x;
  const int b = blockIdx.x >> 6, k = blockIdx.x & 63;
  float s = 0.f;
  if (tid < 64) s = massp[((b << 6) + tid) * Kn + k];
  const float mass = blockReduceSum(s, sb);
  float v[2];
  float sq = 0.f;
#pragma unroll
  for (int u = 0; u < 2; ++u) {
    const int d = tid + (u << 8);
    float val = -mass * centroids[k * Dn + d];
#pragma unroll
    for (int seg = 0; seg < 8; ++seg)
      val += aggp[(((size_t)seg * Bn + b) * Kn + k) * Dn + d];
    v[u] = val;
    sq = fmaf(val, val, sq);
  }
  const float rsq = blockReduceSum(sq, sb);
  const float inv = 1.f / fmaxf(sqrtf(rsq), FEPS);
#pragma unroll
  for (int u = 0; u < 2; ++u)
    out[((size_t)b * Kn + k) * Dn + tid + (u << 8)] = v[u] * inv;
  if (tid == 0) rowsq[b * Kn + k] = rsq * inv * inv;
}

// ---------------------------------------------------------------------------
// kC2: final global L2 norm per batch.
// ---------------------------------------------------------------------------
__global__ __launch_bounds__(256) void kC2(float* __restrict__ out,
                                           const float* __restrict__ rowsq) {
  __shared__ float sg;
  const int b = blockIdx.x, tid = threadIdx.x;
  float v = (tid < 64) ? rowsq[b * Kn + tid] : 0.f;
  if (tid < 64) {
#pragma unroll
    for (int off = 32; off > 0; off >>= 1) v += __shfl_down(v, off, 64);
  }
  if (tid == 0) sg = 1.f / fmaxf(sqrtf(v), FEPS);
  __syncthreads();
  const float inv = sg;
  float* ob = out + (size_t)b * (Kn * Dn);
  for (int t = tid; t < Kn * Dn; t += 256) ob[t] *= inv;
}

// ---------------------------------------------------------------------------
extern "C" void kernel_launch(void* const* d_in, const int* in_sizes, int n_in,
                              void* d_out, int out_size, void* d_ws,
                              size_t ws_size, hipStream_t stream) {
  const float* x = (const float*)d_in[0];
  const float* centroids = (const float*)d_in[1];
  const float* conv_w = (const float*)d_in[2];
  const float* conv_b = (const float*)d_in[3];
  float* out = (float*)d_out;
  float* ws = (float*)d_ws;
  // ws layout (floats):
  //   assign 4,194,304 | invn 65,536 | aggp 4,194,304 | rowsq 1,024
  //   wT 32,768 | massp 65,536
  float* assign = ws;
  float* invn = ws + 4194304;
  float* aggp = ws + 4259840;
  float* rowsq = ws + 8454144;
  float* wT = ws + 8455168;
  float* massp = ws + 8487936;

  kW<<<128, 256, 0, stream>>>(conv_w, wT);
  kA<<<1024, 256, 0, stream>>>(x, wT, conv_b, assign, invn, massp);
  kB<<<1024, 256, 0, stream>>>(x, assign, invn, aggp);
  kC1<<<1024, 256, 0, stream>>>(massp, aggp, centroids, out, rowsq);
  kC2<<<16, 256, 0, stream>>>(out, rowsq);
}

// Round 3
// 198.136 us; speedup vs baseline: 1.6418x; 1.6418x over previous
//
#include <hip/hip_runtime.h>
#include <cstddef>

constexpr int Bn = 16, Dn = 512, Nn = 4096, Kn = 64;
constexpr float FEPS = 1e-12f;

// ---------------------------------------------------------------------------
// kW: transpose conv_w[K][D] -> wT[D][K] so kA can s_load 16 consecutive k.
// ---------------------------------------------------------------------------
__global__ __launch_bounds__(256) void kW(const float* __restrict__ w,
                                          float* __restrict__ wT) {
  const int idx = blockIdx.x * 256 + threadIdx.x;  // 32768 total
  const int d = idx >> 6, k = idx & 63;
  wT[idx] = w[k * Dn + d];
}

// ---------------------------------------------------------------------------
// kA: logits GEMM with W broadcast (s_load), x coalesced, no main-loop LDS.
// Fused x-norm + softmax + per-tile mass partials + TRANSPOSED scaled store:
//   asT[b][n][k] = softmax(logits)[k,n] * invn[n]   (invn folded in here)
//   grid 1024: b = bid>>6, nt = bid&63 (64 n). 4 waves; wave w -> 16 k.
// ---------------------------------------------------------------------------
__global__ __launch_bounds__(256) void kA(const float* __restrict__ x,
                                          const float* __restrict__ wT,
                                          const float* __restrict__ conv_b,
                                          float* __restrict__ asT,
                                          float* __restrict__ massp) {
  __shared__ float red[4][64];
  __shared__ float tbuf[64][65];   // [n][k], +1 pad: 2-way aliasing only
  const int tid = threadIdx.x;
  const int lane = tid & 63;
  const int w = tid >> 6;
  const int kg0 = __builtin_amdgcn_readfirstlane(w << 4);
  const int b = blockIdx.x >> 6;
  const int nt = blockIdx.x & 63;
  const int n0 = nt << 6;
  const float* xp = x + (size_t)b * Dn * Nn + n0 + lane;

  float acc[16];
#pragma unroll
  for (int j = 0; j < 16; ++j) acc[j] = 0.f;
  float ss = 0.f;

#pragma unroll 2
  for (int d = 0; d < Dn; d += 4) {
    float xv[4];
#pragma unroll
    for (int i = 0; i < 4; ++i) xv[i] = xp[(size_t)(d + i) * Nn];
    float wv[4][16];
#pragma unroll
    for (int i = 0; i < 4; ++i)
#pragma unroll
      for (int j = 0; j < 16; ++j) wv[i][j] = wT[(d + i) * Kn + kg0 + j];
#pragma unroll
    for (int i = 0; i < 4; ++i) {
      ss = fmaf(xv[i], xv[i], ss);
#pragma unroll
      for (int j = 0; j < 16; ++j) acc[j] = fmaf(wv[i][j], xv[i], acc[j]);
    }
  }

  // ---- epilogue: invn, logits, softmax over K ----
  const float iv = 1.f / fmaxf(sqrtf(ss), FEPS);
  float lg[16];
#pragma unroll
  for (int j = 0; j < 16; ++j) lg[j] = fmaf(acc[j], iv, conv_b[kg0 + j]);
  float pmax = lg[0];
#pragma unroll
  for (int j = 1; j < 16; ++j) pmax = fmaxf(pmax, lg[j]);
  red[w][lane] = pmax;
  __syncthreads();
  const float gmax = fmaxf(fmaxf(red[0][lane], red[1][lane]),
                           fmaxf(red[2][lane], red[3][lane]));
  __syncthreads();
  float ex[16];
  float psum = 0.f;
#pragma unroll
  for (int j = 0; j < 16; ++j) {
    ex[j] = expf(lg[j] - gmax);
    psum += ex[j];
  }
  red[w][lane] = psum;
  __syncthreads();
  const float gsum =
      (red[0][lane] + red[1][lane]) + (red[2][lane] + red[3][lane]);
  const float isum = 1.f / gsum;

  // mass partials (unscaled) + scaled transpose into LDS
#pragma unroll
  for (int j = 0; j < 16; ++j) {
    const float a = ex[j] * isum;
    float m = a;
#pragma unroll
    for (int off = 1; off < 64; off <<= 1) m += __shfl_xor(m, off);
    if (lane == 0) massp[((b << 6) + nt) * Kn + kg0 + j] = m;
    tbuf[lane][kg0 + j] = a * iv;
  }
  __syncthreads();
  // coalesced write of the [64 n][64 k] tile
  float* atb = asT + ((size_t)b * Nn + n0) * 64;
  const int n = tid >> 2, q = (tid & 3) << 4;
  float vv[16];
#pragma unroll
  for (int i = 0; i < 16; ++i) vv[i] = tbuf[n][q + i];
#pragma unroll
  for (int u = 0; u < 4; ++u)
    *(float4*)(atb + n * 64 + q + 4 * u) =
        make_float4(vv[4 * u], vv[4 * u + 1], vv[4 * u + 2], vv[4 * u + 3]);
}

// ---------------------------------------------------------------------------
// kB v3: agg GEMM, kA's structure. lane = d, wave w -> 16 k, acc[16]/lane.
//   asT rows are contiguous in k -> s_load_dwordx16 broadcast operand.
//   x read as 4x dwordx4 (full 64B line per lane). No LDS, no spill.
//   grid 1024: b = bid>>6, dt = (bid>>3)&7 (64 d), seg = bid&7 (512 n).
// Writes aggp[seg][b][k][d] (deterministic partials).
// ---------------------------------------------------------------------------
__global__ __launch_bounds__(256, 4) void kB(const float* __restrict__ x,
                                             const float* __restrict__ asT,
                                             float* __restrict__ aggp) {
  const int tid = threadIdx.x;
  const int lane = tid & 63;
  const int w = tid >> 6;
  const int kg0 = __builtin_amdgcn_readfirstlane(w << 4);
  const int b = blockIdx.x >> 6;
  const int dt = (blockIdx.x >> 3) & 7;
  const int seg = blockIdx.x & 7;
  const int d = dt * 64 + lane;
  const float* xp = x + (size_t)b * Dn * Nn + (size_t)d * Nn + seg * 512;
  const float* arow = asT + ((size_t)b * Nn + seg * 512) * 64 + kg0;

  float acc[16];
#pragma unroll
  for (int j = 0; j < 16; ++j) acc[j] = 0.f;

  for (int nc = 0; nc < 512; nc += 16) {
    float4 xq[4];
#pragma unroll
    for (int i = 0; i < 4; ++i) xq[i] = *(const float4*)(xp + nc + 4 * i);
    float xv[16];
#pragma unroll
    for (int i = 0; i < 4; ++i) {
      xv[4 * i + 0] = xq[i].x;
      xv[4 * i + 1] = xq[i].y;
      xv[4 * i + 2] = xq[i].z;
      xv[4 * i + 3] = xq[i].w;
    }
#pragma unroll
    for (int t = 0; t < 16; ++t) {
      const float* ar = arow + (size_t)(nc + t) * 64;
#pragma unroll
      for (int j = 0; j < 16; ++j) acc[j] = fmaf(ar[j], xv[t], acc[j]);
    }
  }

  float* outb =
      aggp + (((size_t)(seg * Bn + b)) * Kn + kg0) * Dn + dt * 64 + lane;
#pragma unroll
  for (int j = 0; j < 16; ++j) outb[(size_t)j * Dn] = acc[j];
}

// ---------------------------------------------------------------------------
// kC1: per (b,k): mass from massp; vlad = sum(aggp) - mass*c; intra-norm.
// ---------------------------------------------------------------------------
__device__ __forceinline__ float blockReduceSum(float v, float* sb) {
#pragma unroll
  for (int off = 32; off > 0; off >>= 1) v += __shfl_down(v, off, 64);
  const int lane = threadIdx.x & 63, w = threadIdx.x >> 6;
  if (lane == 0) sb[w] = v;
  __syncthreads();
  if (threadIdx.x == 0) sb[4] = sb[0] + sb[1] + sb[2] + sb[3];
  __syncthreads();
  return sb[4];
}

__global__ __launch_bounds__(256) void kC1(const float* __restrict__ massp,
                                           const float* __restrict__ aggp,
                                           const float* __restrict__ centroids,
                                           float* __restrict__ out,
                                           float* __restrict__ rowsq) {
  __shared__ float sb[5];
  const int tid = threadIdx.x;
  const int b = blockIdx.x >> 6, k = blockIdx.x & 63;
  float s = 0.f;
  if (tid < 64) s = massp[((b << 6) + tid) * Kn + k];
  const float mass = blockReduceSum(s, sb);
  float v[2];
  float sq = 0.f;
#pragma unroll
  for (int u = 0; u < 2; ++u) {
    const int d = tid + (u << 8);
    float val = -mass * centroids[k * Dn + d];
#pragma unroll
    for (int seg = 0; seg < 8; ++seg)
      val += aggp[(((size_t)seg * Bn + b) * Kn + k) * Dn + d];
    v[u] = val;
    sq = fmaf(val, val, sq);
  }
  const float rsq = blockReduceSum(sq, sb);
  const float inv = 1.f / fmaxf(sqrtf(rsq), FEPS);
#pragma unroll
  for (int u = 0; u < 2; ++u)
    out[((size_t)b * Kn + k) * Dn + tid + (u << 8)] = v[u] * inv;
  if (tid == 0) rowsq[b * Kn + k] = rsq * inv * inv;
}

// ---------------------------------------------------------------------------
// kC2: final global L2 norm per batch.
// ---------------------------------------------------------------------------
__global__ __launch_bounds__(256) void kC2(float* __restrict__ out,
                                           const float* __restrict__ rowsq) {
  __shared__ float sg;
  const int b = blockIdx.x, tid = threadIdx.x;
  float v = (tid < 64) ? rowsq[b * Kn + tid] : 0.f;
  if (tid < 64) {
#pragma unroll
    for (int off = 32; off > 0; off >>= 1) v += __shfl_down(v, off, 64);
  }
  if (tid == 0) sg = 1.f / fmaxf(sqrtf(v), FEPS);
  __syncthreads();
  const float inv = sg;
  float* ob = out + (size_t)b * (Kn * Dn);
  for (int t = tid; t < Kn * Dn; t += 256) ob[t] *= inv;
}

// ---------------------------------------------------------------------------
extern "C" void kernel_launch(void* const* d_in, const int* in_sizes, int n_in,
                              void* d_out, int out_size, void* d_ws,
                              size_t ws_size, hipStream_t stream) {
  const float* x = (const float*)d_in[0];
  const float* centroids = (const float*)d_in[1];
  const float* conv_w = (const float*)d_in[2];
  const float* conv_b = (const float*)d_in[3];
  float* out = (float*)d_out;
  float* ws = (float*)d_ws;
  // ws layout (floats):
  //   asT 4,194,304 | aggp 4,194,304 | rowsq 1,024 | wT 32,768 | massp 65,536
  float* asT = ws;
  float* aggp = ws + 4194304;
  float* rowsq = ws + 8388608;
  float* wT = ws + 8389632;
  float* massp = ws + 8422400;

  kW<<<128, 256, 0, stream>>>(conv_w, wT);
  kA<<<1024, 256, 0, stream>>>(x, wT, conv_b, asT, massp);
  kB<<<1024, 256, 0, stream>>>(x, asT, aggp);
  kC1<<<1024, 256, 0, stream>>>(massp, aggp, centroids, out, rowsq);
  kC2<<<16, 256, 0, stream>>>(out, rowsq);
}